// Round 9
// baseline (99.784 us; speedup 1.0000x reference)
//
#include <hip/hip_runtime.h>
#include <hip/hip_bf16.h>

typedef float    f32x4  __attribute__((ext_vector_type(4)));
typedef short    bf16x8 __attribute__((ext_vector_type(8)));
typedef unsigned u32x2  __attribute__((ext_vector_type(2)));

#define Bsz   8192
#define Dsz   64
#define Hsz   128
#define Tsz   41
#define TROWS 16     // batch rows per tile
#define NT    512    // 8 waves: 0-3 = tile A, 4-7 = tile B (anti-phased)

#define MFMA(a,b,c) __builtin_amdgcn_mfma_f32_16x16x32_bf16((a),(b),(c),0,0,0)

__device__ __forceinline__ float fast_tanh(float x) {
    float ax = __builtin_fabsf(x);
    float e  = __expf(-2.0f * ax);
    float r  = (1.0f - e) * __builtin_amdgcn_rcpf(1.0f + e);
    return __builtin_copysignf(r, x);
}

__device__ __forceinline__ unsigned short bf2u(__hip_bfloat16 h) {
    union { __hip_bfloat16 b; unsigned short u; } v; v.b = h; return v.u;
}

union FragU { bf16x8 f; unsigned short h[8]; };

// split 8 f32 into hi/lo bf16 fragments (weights, init only)
__device__ __forceinline__ void split8(const float* x, bf16x8& hi, bf16x8& lo) {
    FragU H, L;
    #pragma unroll
    for (int i = 0; i < 8; ++i) {
        __hip_bfloat16 hb = __float2bfloat16(x[i]);
        H.h[i] = bf2u(hb);
        L.h[i] = bf2u(__float2bfloat16(x[i] - __bfloat162float(hb)));
    }
    hi = H.f; lo = L.f;
}

// split f32x4 -> packed H (2 dwords) and packed L (R6 version — library casts)
__device__ __forceinline__ void splitq(const f32x4& x, u32x2& H, u32x2& L) {
    unsigned short h0 = bf2u(__float2bfloat16(x[0]));
    unsigned short h1 = bf2u(__float2bfloat16(x[1]));
    unsigned short h2 = bf2u(__float2bfloat16(x[2]));
    unsigned short h3 = bf2u(__float2bfloat16(x[3]));
    float f0 = __uint_as_float((unsigned)h0 << 16);
    float f1 = __uint_as_float((unsigned)h1 << 16);
    float f2 = __uint_as_float((unsigned)h2 << 16);
    float f3 = __uint_as_float((unsigned)h3 << 16);
    unsigned short l0 = bf2u(__float2bfloat16(x[0] - f0));
    unsigned short l1 = bf2u(__float2bfloat16(x[1] - f1));
    unsigned short l2 = bf2u(__float2bfloat16(x[2] - f2));
    unsigned short l3 = bf2u(__float2bfloat16(x[3] - f3));
    H[0] = (unsigned)h0 | ((unsigned)h1 << 16);
    H[1] = (unsigned)h2 | ((unsigned)h3 << 16);
    L[0] = (unsigned)l0 | ((unsigned)l1 << 16);
    L[1] = (unsigned)l2 | ((unsigned)l3 << 16);
}

__device__ __forceinline__ bf16x8 ldb128(const unsigned short* base, int byteoff) {
    return *(const bf16x8*)((const char*)base + byteoff);
}
__device__ __forceinline__ void stb64(unsigned short* base, int byteoff, u32x2 v) {
    *(u32x2*)((char*)base + byteoff) = v;
}

__global__ __launch_bounds__(NT, 2)
void ode_mfma9(const float* __restrict__ z0, const float* __restrict__ t,
               const float* __restrict__ W1, const float* __restrict__ b1,
               const float* __restrict__ W2, const float* __restrict__ b2,
               float* __restrict__ out)
{
    // per-tile bf16 H/L operand tiles, [tile][batch_row][feature], XOR-swizzled bytes
    __shared__ __align__(16) unsigned short zHs[2][TROWS * Dsz], zLs[2][TROWS * Dsz];
    __shared__ __align__(16) unsigned short aHs[2][TROWS * Hsz], aLs[2][TROWS * Hsz];
    __shared__ float ts[Tsz];

    const int tid  = threadIdx.x;
    const int tb   = tid >> 8;          // 0: waves 0-3 (tile A), 1: waves 4-7 (tile B)
    const int lane = tid & 63;
    const int w    = (tid >> 6) & 3;    // wave-within-group: layer1 h 32w..+31, layer2 d 16w..+15
    const int g    = lane >> 4;
    const int c    = lane & 15;         // batch row within tile
    const int r0   = blockIdx.x * (2 * TROWS) + tb * TROWS;

    if (tid < Tsz) ts[tid] = t[tid];

    unsigned short* zH = zHs[tb];
    unsigned short* zL = zLs[tb];
    unsigned short* aH = aHs[tb];
    unsigned short* aL = aLs[tb];

    // ---- z master in registers: zreg[reg] = z[batch=c][d = 16w + 4g + reg] ----
    f32x4 zreg = *(const f32x4*)&z0[(r0 + c) * Dsz + 16*w + 4*g];

    // ---- W1^T A-fragments: lane holds W1T[h=16(2w+nt)+c][d=32kt+8g+i] ----
    bf16x8 w1tH[2][2], w1tL[2][2];   // [nt][kt]
    #pragma unroll
    for (int nt = 0; nt < 2; ++nt) {
        const int n = 32*w + 16*nt + c;
        #pragma unroll
        for (int kt = 0; kt < 2; ++kt) {
            float tmp[8];
            #pragma unroll
            for (int i = 0; i < 8; ++i) tmp[i] = W1[(32*kt + 8*g + i) * Hsz + n];
            split8(tmp, w1tH[nt][kt], w1tL[nt][kt]);
        }
    }
    // ---- W2^T A-fragments: lane holds W2T[d=16w+c][h=32kt2+8g+i] ----
    bf16x8 w2tH[4], w2tL[4];         // [kt2]
    {
        const int n = 16*w + c;
        #pragma unroll
        for (int kt2 = 0; kt2 < 4; ++kt2) {
            float tmp[8];
            #pragma unroll
            for (int i = 0; i < 8; ++i) tmp[i] = W2[(32*kt2 + 8*g + i) * Dsz + n];
            split8(tmp, w2tH[kt2], w2tL[kt2]);
        }
    }
    f32x4 b1v[2], b2v;
    #pragma unroll
    for (int nt = 0; nt < 2; ++nt)
        #pragma unroll
        for (int reg = 0; reg < 4; ++reg)
            b1v[nt][reg] = b1[16*(2*w + nt) + 4*g + reg];
    #pragma unroll
    for (int reg = 0; reg < 4; ++reg) b2v[reg] = b2[16*w + 4*g + reg];

    // ---- loop-invariant swizzled LDS byte offsets (within-tile, same as R6) ----
    const int zw = (c*128 + (16*w + 4*g)*2) ^ ((c & 7) << 4);          // b64 write
    int zrd[2], aw[2], ard[4];
    #pragma unroll
    for (int kt = 0; kt < 2; ++kt)
        zrd[kt] = (c*128 + (32*kt + 8*g)*2) ^ ((c & 7) << 4);          // b128 read
    #pragma unroll
    for (int nt = 0; nt < 2; ++nt)
        aw[nt] = (c*256 + (32*w + 16*nt + 4*g)*2) ^ ((c & 7) << 4);    // b64 write
    #pragma unroll
    for (int kt2 = 0; kt2 < 4; ++kt2)
        ard[kt2] = (c*256 + (32*kt2 + 8*g)*2) ^ ((c & 7) << 4);        // b128 read

    auto z_to_lds = [&]() {
        u32x2 H, L;
        splitq(zreg, H, L);
        stb64(zH, zw, H);
        stb64(zL, zw, L);
    };

    // ---- layer 1: a^T = tanh(W1^T @ z^T + b1) -> a-tile (reads own z-tile) ----
    auto do_L1 = [&]() {
        bf16x8 zh0 = ldb128(zH, zrd[0]), zh1 = ldb128(zH, zrd[1]);
        bf16x8 zl0 = ldb128(zL, zrd[0]), zl1 = ldb128(zL, zrd[1]);
        #pragma unroll
        for (int nt = 0; nt < 2; ++nt) {
            f32x4 aA = b1v[nt];
            f32x4 aB = {0,0,0,0}, aC = {0,0,0,0};
            aA = MFMA(w1tH[nt][0], zh0, aA);
            aB = MFMA(w1tH[nt][0], zl0, aB);
            aC = MFMA(w1tL[nt][0], zh0, aC);
            aA = MFMA(w1tH[nt][1], zh1, aA);
            aB = MFMA(w1tH[nt][1], zl1, aB);
            aC = MFMA(w1tL[nt][1], zh1, aC);
            f32x4 av = (aA + aB) + aC;
            f32x4 tv;
            #pragma unroll
            for (int reg = 0; reg < 4; ++reg) tv[reg] = fast_tanh(av[reg]);
            u32x2 H, L;
            splitq(tv, H, L);
            stb64(aH, aw[nt], H);
            stb64(aL, aw[nt], L);
        }
    };

    // ---- layer 2: dz^T = W2^T @ a^T + b2; z += h*dz; z -> z-tile ----
    auto do_L2 = [&](float h) {
        bf16x8 ah0 = ldb128(aH, ard[0]), ah1 = ldb128(aH, ard[1]);
        bf16x8 ah2 = ldb128(aH, ard[2]), ah3 = ldb128(aH, ard[3]);
        bf16x8 al0 = ldb128(aL, ard[0]), al1 = ldb128(aL, ard[1]);
        bf16x8 al2 = ldb128(aL, ard[2]), al3 = ldb128(aL, ard[3]);
        f32x4 dA = b2v;
        f32x4 dB = {0,0,0,0}, dC = {0,0,0,0};
        dA = MFMA(w2tH[0], ah0, dA);
        dB = MFMA(w2tH[0], al0, dB);
        dC = MFMA(w2tL[0], ah0, dC);
        dA = MFMA(w2tH[1], ah1, dA);
        dB = MFMA(w2tH[1], al1, dB);
        dC = MFMA(w2tL[1], ah1, dC);
        dA = MFMA(w2tH[2], ah2, dA);
        dB = MFMA(w2tH[2], al2, dB);
        dC = MFMA(w2tL[2], ah2, dC);
        dA = MFMA(w2tH[3], ah3, dA);
        dB = MFMA(w2tH[3], al3, dB);
        dC = MFMA(w2tL[3], ah3, dC);
        f32x4 dz = (dA + dB) + dC;
        zreg += h * dz;
        z_to_lds();
    };

    z_to_lds();
    __syncthreads();

    const int n_steps = (int)ceilf(fabsf(ts[1] - ts[0]) / 0.05f);   // = 2 (exact in f32)

    // ---- staggered pipeline: B runs half a substep behind A ----
    // prologue: A computes its first L1 (B idle this phase)
    if (tb == 0) do_L1();
    __syncthreads();

    for (int iv = 0; iv < Tsz - 1; ++iv) {
        const float h = (ts[iv + 1] - ts[iv]) / (float)n_steps;
        for (int ss = 0; ss < n_steps; ++ss) {
            // phase 1: A.L2(s)  ||  B.L1(s)
            if (tb == 0) do_L2(h); else do_L1();
            __syncthreads();
            // phase 2: A.L1(s+1)  ||  B.L2(s)   (A skips on very last substep)
            const bool last = (iv == Tsz - 2) && (ss == n_steps - 1);
            if (tb == 0) { if (!last) do_L1(); } else { do_L2(h); }
            __syncthreads();
        }
    }

    // ---- write result (one dwordx4 per lane) ----
    *(f32x4*)&out[(r0 + c) * Dsz + 16*w + 4*g] = zreg;
}

extern "C" void kernel_launch(void* const* d_in, const int* in_sizes, int n_in,
                              void* d_out, int out_size, void* d_ws, size_t ws_size,
                              hipStream_t stream) {
    const float* z0 = (const float*)d_in[0];
    const float* t  = (const float*)d_in[1];
    const float* W1 = (const float*)d_in[2];
    const float* b1 = (const float*)d_in[3];
    const float* W2 = (const float*)d_in[4];
    const float* b2 = (const float*)d_in[5];
    float* out = (float*)d_out;
    (void)in_sizes; (void)n_in; (void)out_size; (void)d_ws; (void)ws_size;

    ode_mfma9<<<dim3(Bsz / (2 * TROWS)), dim3(NT), 0, stream>>>(z0, t, W1, b1, W2, b2, out);
}

// Round 10
// 92.427 us; speedup vs baseline: 1.0796x; 1.0796x over previous
//
#include <hip/hip_runtime.h>
#include <hip/hip_bf16.h>

typedef float    f32x4  __attribute__((ext_vector_type(4)));
typedef short    bf16x8 __attribute__((ext_vector_type(8)));
typedef unsigned u32x2  __attribute__((ext_vector_type(2)));

#define Bsz  8192
#define Dsz  64
#define Hsz  128
#define Tsz  41
#define ROWS 16
#define NT   256

#define MFMA(a,b,c) __builtin_amdgcn_mfma_f32_16x16x32_bf16((a),(b),(c),0,0,0)

// tanh(x) = 1 - 2/(1 + e^{2x}) — sign-free, exact tails, ~1ulp abs err near 0
__device__ __forceinline__ float fast_tanh(float x) {
    float e = __expf(2.0f * x);
    float r = __builtin_amdgcn_rcpf(1.0f + e);
    return __builtin_fmaf(-2.0f, r, 1.0f);
}

__device__ __forceinline__ unsigned short bf2u(__hip_bfloat16 h) {
    union { __hip_bfloat16 b; unsigned short u; } v; v.b = h; return v.u;
}

union FragU { bf16x8 f; unsigned short h[8]; };

// split 8 f32 into hi/lo bf16 fragments (weights, init only)
__device__ __forceinline__ void split8(const float* x, bf16x8& hi, bf16x8& lo) {
    FragU H, L;
    #pragma unroll
    for (int i = 0; i < 8; ++i) {
        __hip_bfloat16 hb = __float2bfloat16(x[i]);
        H.h[i] = bf2u(hb);
        L.h[i] = bf2u(__float2bfloat16(x[i] - __bfloat162float(hb)));
    }
    hi = H.f; lo = L.f;
}

// split f32x4 -> packed H (2 dwords) and packed L (compiler lowers casts to cvt_pk)
__device__ __forceinline__ void splitq(const f32x4& x, u32x2& H, u32x2& L) {
    unsigned short h0 = bf2u(__float2bfloat16(x[0]));
    unsigned short h1 = bf2u(__float2bfloat16(x[1]));
    unsigned short h2 = bf2u(__float2bfloat16(x[2]));
    unsigned short h3 = bf2u(__float2bfloat16(x[3]));
    float f0 = __uint_as_float((unsigned)h0 << 16);
    float f1 = __uint_as_float((unsigned)h1 << 16);
    float f2 = __uint_as_float((unsigned)h2 << 16);
    float f3 = __uint_as_float((unsigned)h3 << 16);
    unsigned short l0 = bf2u(__float2bfloat16(x[0] - f0));
    unsigned short l1 = bf2u(__float2bfloat16(x[1] - f1));
    unsigned short l2 = bf2u(__float2bfloat16(x[2] - f2));
    unsigned short l3 = bf2u(__float2bfloat16(x[3] - f3));
    H[0] = (unsigned)h0 | ((unsigned)h1 << 16);
    H[1] = (unsigned)h2 | ((unsigned)h3 << 16);
    L[0] = (unsigned)l0 | ((unsigned)l1 << 16);
    L[1] = (unsigned)l2 | ((unsigned)l3 << 16);
}

__device__ __forceinline__ bf16x8 ldb128(const unsigned short* base, int byteoff) {
    return *(const bf16x8*)((const char*)base + byteoff);
}
__device__ __forceinline__ void stb64(unsigned short* base, int byteoff, u32x2 v) {
    *(u32x2*)((char*)base + byteoff) = v;
}

__global__ __launch_bounds__(NT, 2)
void ode_mfma10(const float* __restrict__ z0, const float* __restrict__ t,
                const float* __restrict__ W1, const float* __restrict__ b1,
                const float* __restrict__ W2, const float* __restrict__ b2,
                float* __restrict__ out)
{
    // bf16 H/L tiles, [batch_row][feature], byte-index XOR-swizzled by (row&7)<<4
    __shared__ __align__(16) unsigned short zHs[ROWS * Dsz], zLs[ROWS * Dsz];
    __shared__ __align__(16) unsigned short aHs[ROWS * Hsz], aLs[ROWS * Hsz];
    __shared__ float ts[Tsz];

    const int tid  = threadIdx.x;
    const int lane = tid & 63;
    const int w    = tid >> 6;   // wave: layer1 h-cols 32w..+31, layer2 d-cols 16w..+15
    const int g    = lane >> 4;
    const int c    = lane & 15;  // batch row within tile
    const int r0   = blockIdx.x * ROWS;

    if (tid < Tsz) ts[tid] = t[tid];

    // ---- z master in registers: zreg[reg] = z[batch=c][d = 16w + 4g + reg] ----
    f32x4 zreg = *(const f32x4*)&z0[(r0 + c) * Dsz + 16*w + 4*g];

    // ---- W1^T A-fragments: lane holds W1T[h=16(2w+nt)+c][d=32kt+8g+i] ----
    bf16x8 w1tH[2][2], w1tL[2][2];   // [nt][kt]
    #pragma unroll
    for (int nt = 0; nt < 2; ++nt) {
        const int n = 32*w + 16*nt + c;
        #pragma unroll
        for (int kt = 0; kt < 2; ++kt) {
            float tmp[8];
            #pragma unroll
            for (int i = 0; i < 8; ++i) tmp[i] = W1[(32*kt + 8*g + i) * Hsz + n];
            split8(tmp, w1tH[nt][kt], w1tL[nt][kt]);
        }
    }
    // ---- W2^T A-fragments: lane holds W2T[d=16w+c][h=32kt2+8g+i] ----
    bf16x8 w2tH[4], w2tL[4];         // [kt2]
    {
        const int n = 16*w + c;
        #pragma unroll
        for (int kt2 = 0; kt2 < 4; ++kt2) {
            float tmp[8];
            #pragma unroll
            for (int i = 0; i < 8; ++i) tmp[i] = W2[(32*kt2 + 8*g + i) * Dsz + n];
            split8(tmp, w2tH[kt2], w2tL[kt2]);
        }
    }
    f32x4 b1v[2], b2v;
    #pragma unroll
    for (int nt = 0; nt < 2; ++nt)
        #pragma unroll
        for (int reg = 0; reg < 4; ++reg)
            b1v[nt][reg] = b1[16*(2*w + nt) + 4*g + reg];
    #pragma unroll
    for (int reg = 0; reg < 4; ++reg) b2v[reg] = b2[16*w + 4*g + reg];

    // ---- loop-invariant swizzled LDS byte offsets ----
    const int zw = (c*128 + (16*w + 4*g)*2) ^ ((c & 7) << 4);          // b64 write
    int zrd[2], aw[2], ard[4];
    #pragma unroll
    for (int kt = 0; kt < 2; ++kt)
        zrd[kt] = (c*128 + (32*kt + 8*g)*2) ^ ((c & 7) << 4);          // b128 read
    #pragma unroll
    for (int nt = 0; nt < 2; ++nt)
        aw[nt] = (c*256 + (32*w + 16*nt + 4*g)*2) ^ ((c & 7) << 4);    // b64 write
    #pragma unroll
    for (int kt2 = 0; kt2 < 4; ++kt2)
        ard[kt2] = (c*256 + (32*kt2 + 8*g)*2) ^ ((c & 7) << 4);        // b128 read

    auto z_to_lds = [&]() {
        u32x2 H, L;
        splitq(zreg, H, L);
        stb64(zHs, zw, H);
        stb64(zLs, zw, L);
    };

    z_to_lds();
    __syncthreads();

    const int n_steps = (int)ceilf(fabsf(ts[1] - ts[0]) / 0.05f);   // = 2 (exact in f32)

    for (int iv = 0; iv < Tsz - 1; ++iv) {
        const float h = (ts[iv + 1] - ts[iv]) / (float)n_steps;
        for (int s = 0; s < n_steps; ++s) {
            // ---- layer 1 (transposed): MFMA cluster first (both nt), VALU tail after ----
            bf16x8 zh0 = ldb128(zHs, zrd[0]), zh1 = ldb128(zHs, zrd[1]);
            bf16x8 zl0 = ldb128(zLs, zrd[0]), zl1 = ldb128(zLs, zrd[1]);
            f32x4 aA0 = b1v[0], aB0 = {0,0,0,0}, aC0 = {0,0,0,0};
            f32x4 aA1 = b1v[1], aB1 = {0,0,0,0}, aC1 = {0,0,0,0};
            aA0 = MFMA(w1tH[0][0], zh0, aA0);  aA1 = MFMA(w1tH[1][0], zh0, aA1);
            aB0 = MFMA(w1tH[0][0], zl0, aB0);  aB1 = MFMA(w1tH[1][0], zl0, aB1);
            aC0 = MFMA(w1tL[0][0], zh0, aC0);  aC1 = MFMA(w1tL[1][0], zh0, aC1);
            aA0 = MFMA(w1tH[0][1], zh1, aA0);  aA1 = MFMA(w1tH[1][1], zh1, aA1);
            aB0 = MFMA(w1tH[0][1], zl1, aB0);  aB1 = MFMA(w1tH[1][1], zl1, aB1);
            aC0 = MFMA(w1tL[0][1], zh1, aC0);  aC1 = MFMA(w1tL[1][1], zh1, aC1);
            {
                f32x4 av0 = (aA0 + aB0) + aC0;
                f32x4 av1 = (aA1 + aB1) + aC1;
                f32x4 tv0, tv1;
                #pragma unroll
                for (int reg = 0; reg < 4; ++reg) tv0[reg] = fast_tanh(av0[reg]);
                #pragma unroll
                for (int reg = 0; reg < 4; ++reg) tv1[reg] = fast_tanh(av1[reg]);
                u32x2 H0, L0, H1, L1;
                splitq(tv0, H0, L0);
                splitq(tv1, H1, L1);
                stb64(aHs, aw[0], H0);
                stb64(aLs, aw[0], L0);
                stb64(aHs, aw[1], H1);
                stb64(aLs, aw[1], L1);
            }
            __syncthreads();
            // ---- layer 2 (transposed): dz^T = W2^T @ a^T + b2 ----
            bf16x8 ah0 = ldb128(aHs, ard[0]), ah1 = ldb128(aHs, ard[1]);
            bf16x8 ah2 = ldb128(aHs, ard[2]), ah3 = ldb128(aHs, ard[3]);
            bf16x8 al0 = ldb128(aLs, ard[0]), al1 = ldb128(aLs, ard[1]);
            bf16x8 al2 = ldb128(aLs, ard[2]), al3 = ldb128(aLs, ard[3]);
            f32x4 dA = b2v;
            f32x4 dB = {0,0,0,0}, dC = {0,0,0,0};
            dA = MFMA(w2tH[0], ah0, dA);
            dB = MFMA(w2tH[0], al0, dB);
            dC = MFMA(w2tL[0], ah0, dC);
            dA = MFMA(w2tH[1], ah1, dA);
            dB = MFMA(w2tH[1], al1, dB);
            dC = MFMA(w2tL[1], ah1, dC);
            dA = MFMA(w2tH[2], ah2, dA);
            dB = MFMA(w2tH[2], al2, dB);
            dC = MFMA(w2tL[2], ah2, dC);
            dA = MFMA(w2tH[3], ah3, dA);
            dB = MFMA(w2tH[3], al3, dB);
            dC = MFMA(w2tL[3], ah3, dC);
            f32x4 dz = (dA + dB) + dC;
            zreg += h * dz;
            z_to_lds();                  // 2 b64 writes
            __syncthreads();
        }
    }

    // ---- write result (one dwordx4 per lane) ----
    *(f32x4*)&out[(r0 + c) * Dsz + 16*w + 4*g] = zreg;
}

extern "C" void kernel_launch(void* const* d_in, const int* in_sizes, int n_in,
                              void* d_out, int out_size, void* d_ws, size_t ws_size,
                              hipStream_t stream) {
    const float* z0 = (const float*)d_in[0];
    const float* t  = (const float*)d_in[1];
    const float* W1 = (const float*)d_in[2];
    const float* b1 = (const float*)d_in[3];
    const float* W2 = (const float*)d_in[4];
    const float* b2 = (const float*)d_in[5];
    float* out = (float*)d_out;
    (void)in_sizes; (void)n_in; (void)out_size; (void)d_ws; (void)ws_size;

    ode_mfma10<<<dim3(Bsz / ROWS), dim3(NT), 0, stream>>>(z0, t, W1, b1, W2, b2, out);
}